// Round 11
// baseline (650.704 us; speedup 1.0000x reference)
//
#include <hip/hip_runtime.h>
#include <cstdint>
#include <cstddef>

#define B_ 64
#define S_ 8
#define D_ 2048
#define V_ 128000
#define CAND_CAP 8192
#define NBLK 500            // V_/256 GEMM blocks

typedef __bf16 v8bf __attribute__((ext_vector_type(8)));
typedef float  v4f  __attribute__((ext_vector_type(4)));

// ---------------- threefry2x32 (JAX-compatible) ----------------
__device__ __forceinline__ uint32_t rotl32(uint32_t x, int r){ return (x << r) | (x >> (32 - r)); }
__device__ __forceinline__ void tfround(uint32_t& x0, uint32_t& x1, int r){
  x0 += x1; x1 = rotl32(x1, r); x1 ^= x0;
}
__device__ __forceinline__ void threefry2x32(uint32_t k0, uint32_t k1, uint32_t c0, uint32_t c1,
                                             uint32_t& o0, uint32_t& o1){
  uint32_t ks2 = k0 ^ k1 ^ 0x1BD11BDAu;
  uint32_t x0 = c0 + k0, x1 = c1 + k1;
  tfround(x0,x1,13); tfround(x0,x1,15); tfround(x0,x1,26); tfround(x0,x1,6);
  x0 += k1; x1 += ks2 + 1u;
  tfround(x0,x1,17); tfround(x0,x1,29); tfround(x0,x1,16); tfround(x0,x1,24);
  x0 += ks2; x1 += k0 + 2u;
  tfround(x0,x1,13); tfround(x0,x1,15); tfround(x0,x1,26); tfround(x0,x1,6);
  x0 += k0; x1 += k1 + 3u;
  tfround(x0,x1,17); tfround(x0,x1,29); tfround(x0,x1,16); tfround(x0,x1,24);
  x0 += k1; x1 += ks2 + 4u;
  tfround(x0,x1,13); tfround(x0,x1,15); tfround(x0,x1,26); tfround(x0,x1,6);
  x0 += ks2; x1 += k0 + 5u;
  o0 = x0; o1 = x1;
}

#define JAX_PARTITIONABLE 1

__device__ __forceinline__ float gumbel_at(uint32_t b, uint32_t v){
  uint32_t j = b * (uint32_t)V_ + v;
  uint32_t bits;
#if JAX_PARTITIONABLE
  uint32_t o0, o1; threefry2x32(0u, 42u, 0u, j, o0, o1);
  bits = o0 ^ o1;
#else
  const uint32_t HALF = 4096000u;  // B*V/2
  uint32_t o0, o1;
  if (j < HALF){ threefry2x32(0u, 42u, j, j + HALF, o0, o1); bits = o0; }
  else        { threefry2x32(0u, 42u, j - HALF, j, o0, o1); bits = o1; }
#endif
  uint32_t fb = (bits >> 9) | 0x3F800000u;
  float f = __uint_as_float(fb) - 1.0f;
  const float TINY = 1.17549435e-38f;
  float u = fmaxf(TINY, f + TINY);
  return -logf(-logf(u));
}

__device__ __forceinline__ unsigned ordkey(float f){
  unsigned u = __float_as_uint(f);
  return (u & 0x80000000u) ? ~u : (u | 0x80000000u);
}
__device__ __forceinline__ float ordinv(unsigned o){
  unsigned u = (o & 0x80000000u) ? (o & 0x7FFFFFFFu) : ~o;
  return __uint_as_float(u);
}

__device__ __forceinline__ v8bf ld_bf8(const unsigned short* p){
  uint4 u = *reinterpret_cast<const uint4*>(p);
  return __builtin_bit_cast(v8bf, u);
}

// ---------------- kernels ----------------

// gather h at out_pos, split fp32 -> bf16 hi/lo in FRAGMENT-PACKED layout:
// Apk[(((s*4 + mi)*64) + kg*16 + r16)*8 + j], s = k>>5, kg=(k>>3)&3, j=k&7, mi=b>>4, r16=b&15
__global__ __launch_bounds__(256) void Sampler_gather(const float* __restrict__ x,
    const int* __restrict__ out_pos, unsigned short* __restrict__ hhi,
    unsigned short* __restrict__ hlo, unsigned* __restrict__ cnt,
    unsigned* __restrict__ Mo){
  const int pos = out_pos[0];
  int i = blockIdx.x * 256 + threadIdx.x;
  if (i < B_ * D_){
    int bq = i >> 11;          // b
    int kq = i & 2047;         // k
    float v = x[((size_t)bq * S_ + pos) * D_ + kq];
    __bf16 hb = (__bf16)v;
    float hf = (float)hb;
    __bf16 lb = (__bf16)(v - hf);
    int s  = kq >> 5;
    int kg = (kq >> 3) & 3;
    int j  = kq & 7;
    int mi = bq >> 4;
    int r16 = bq & 15;
    int idx = (((s * 4 + mi) * 64) + kg * 16 + r16) * 8 + j;
    hhi[idx] = __builtin_bit_cast(unsigned short, hb);
    hlo[idx] = __builtin_bit_cast(unsigned short, lb);
  }
  if (i < 64){ cnt[i] = 0; Mo[i] = 0; }
}

// Split-bf16 MFMA GEMM. R6 geometry (BN=256, BK=32, XOR-swizzled stage+read,
// packed A, 2x32KB LDS dbuf, 2 blocks/CU) with REGISTER-STAGED deep pipeline:
// two alternating reg sets hold chunks c+1 (being written to LDS) and c+2
// (in flight from HBM); ds_write's compiler-exact vmcnt leaves c+2 flying;
// raw s_barrier with lgkmcnt-only wait (no vmcnt(0) drain). HBM queue never
// empties -> sustained in-flight 64-128 KB/CU.
__global__ __launch_bounds__(256, 2) void Sampler_gemm(
    const unsigned short* __restrict__ hhi,  // packed A hi
    const unsigned short* __restrict__ hlo,  // packed A lo
    const float* __restrict__ emb,           // [V_][D_]
    const float* __restrict__ bias,          // [V_]
    float* __restrict__ out)                 // [64][V_]
{
  __shared__ float Bs[2][256 * 32];          // 2 x 32 KB
  const int tid  = threadIdx.x;
  const int wid  = tid >> 6;
  const int lane = tid & 63;
  const int r16  = lane & 15;
  const int kg   = lane >> 4;                // 0..3
  const int vbase = (blockIdx.x << 8) + (wid << 6);

  // staging map (identical to R6): thread t owns LDS bytes t*16 + p*4096,
  // source granule inverse-swizzled: (t&7) ^ (row&7), row = t>>3 (+32p)
  const int srow = tid >> 3;
  const int hsrc = (tid & 7) ^ (srow & 7);
  const float* sbase = emb + (size_t)((blockIdx.x << 8) + srow) * D_ + hsrc * 4;

  // read constants: phys granules for this lane's k-slice (row&7 == r16&7)
  const int h0 = ((2 * kg)     ^ (r16 & 7)) * 4;  // in floats
  const int h1 = ((2 * kg + 1) ^ (r16 & 7)) * 4;

  v4f acc[4][4];
#pragma unroll
  for (int mi = 0; mi < 4; ++mi)
#pragma unroll
    for (int ni = 0; ni < 4; ++ni) acc[mi][ni] = (v4f){0.f, 0.f, 0.f, 0.f};

  const unsigned short* hhb = hhi + lane * 8;
  const unsigned short* hlb = hlo + lane * 8;

  float4 S0[8], S1[8];                       // chunk k lives in S(k&1)

  auto LOADS = [&](int c, float4 (&S)[8]){   // issue 8 global_load_dwordx4
#pragma unroll
    for (int p = 0; p < 8; ++p)
      S[p] = *(const float4*)(sbase + (size_t)p * 32 * D_ + c * 32);
  };
  auto WRITES = [&](int c, float4 (&S)[8]){  // 8 ds_write_b128 (linear dst)
    float* dst = &Bs[c & 1][tid * 4];
#pragma unroll
    for (int p = 0; p < 8; ++p)
      *(float4*)(dst + p * 1024) = S[p];
  };

  // prologue: chunk0 -> S0, chunk1 -> S1; write chunk0 (waits S0, leaves S1 flying)
  LOADS(0, S0);
  LOADS(1, S1);
  WRITES(0, S0);
  asm volatile("s_waitcnt lgkmcnt(0)" ::: "memory");
  __builtin_amdgcn_s_barrier();
  asm volatile("" ::: "memory");

#pragma unroll 1
  for (int c = 0; c < 64; ++c){
    const int cur = c & 1;

    // (1) A fragments for chunk c (L2-resident) — MUST issue first so the
    //     compute's vmcnt wait for A leaves chunk c+2 in flight.
    v8bf ah[4], al[4];
#pragma unroll
    for (int mi = 0; mi < 4; ++mi){
      const int fo = (c * 4 + mi) * 512;
      ah[mi] = ld_bf8(hhb + fo);
      al[mi] = ld_bf8(hlb + fo);
    }
    __builtin_amdgcn_sched_barrier(0);

    // (2) issue chunk c+2 loads into the set freed by last iter's WRITES
    if (c + 2 < 64){
      if (cur == 0) LOADS(c + 2, S0); else LOADS(c + 2, S1);
    }
    __builtin_amdgcn_sched_barrier(0);

    // (3) write chunk c+1 (loaded one iter ago) to the other LDS buffer;
    //     compiler-exact vmcnt leaves A(c) + chunk(c+2) outstanding.
    if (c + 1 < 64){
      if (cur == 0) WRITES(c + 1, S1); else WRITES(c + 1, S0);
    }

    // (4) compute from current buffer
    const float* bbase = &Bs[cur][0];
#pragma unroll
    for (int ni = 0; ni < 4; ++ni){
      const int r = (wid << 6) + (ni << 4) + r16;
      const float* bp = bbase + r * 32;
      float4 b0 = *(const float4*)(bp + h0);   // k = 8kg .. +3
      float4 b1 = *(const float4*)(bp + h1);   // k = 8kg+4 .. +7
      float xf[8] = { b0.x, b0.y, b0.z, b0.w, b1.x, b1.y, b1.z, b1.w };
      v8bf bh, bl;
#pragma unroll
      for (int j = 0; j < 8; ++j){
        float v = xf[j];
        __bf16 hb = (__bf16)v;
        float hf = (float)hb;
        bh[j] = hb;
        bl[j] = (__bf16)(v - hf);
      }
#pragma unroll
      for (int mi = 0; mi < 4; ++mi){
        acc[mi][ni] = __builtin_amdgcn_mfma_f32_16x16x32_bf16(ah[mi], bh, acc[mi][ni], 0, 0, 0);
        acc[mi][ni] = __builtin_amdgcn_mfma_f32_16x16x32_bf16(al[mi], bh, acc[mi][ni], 0, 0, 0);
        acc[mi][ni] = __builtin_amdgcn_mfma_f32_16x16x32_bf16(ah[mi], bl, acc[mi][ni], 0, 0, 0);
      }
    }

    // (5) lgkm-only wait + raw barrier: ds_writes visible, vmcnt NOT drained
    asm volatile("s_waitcnt lgkmcnt(0)" ::: "memory");
    __builtin_amdgcn_s_barrier();
    asm volatile("" ::: "memory");
  }

  // epilogue: + bias
#pragma unroll
  for (int ni = 0; ni < 4; ++ni){
    const int v = vbase + 16 * ni + r16;
    const float bv = bias[v];
#pragma unroll
    for (int mi = 0; mi < 4; ++mi){
#pragma unroll
      for (int r = 0; r < 4; ++r){
        const int b = 16 * mi + 4 * kg + r;
        out[(size_t)b * V_ + v] = acc[mi][ni][r] + bv;
      }
    }
  }
}

// per-row max via 4 column-slices per row, atomicMax on ordkey
__global__ __launch_bounds__(256) void Sampler_rowmax(const float* __restrict__ logits,
    unsigned* __restrict__ Mo){
  __shared__ float red[4];
  const int b = blockIdx.x >> 2, sl = blockIdx.x & 3;
  const int tid = threadIdx.x;
  const float4* row = (const float4*)(logits + (size_t)b * V_ + sl * 32000);
  float m = -3.4e38f;
  for (int i = tid; i < 8000; i += 256){
    float4 v = row[i];
    m = fmaxf(m, fmaxf(fmaxf(v.x, v.y), fmaxf(v.z, v.w)));
  }
#pragma unroll
  for (int off = 32; off; off >>= 1) m = fmaxf(m, __shfl_down(m, off));
  if ((tid & 63) == 0) red[tid >> 6] = m;
  __syncthreads();
  if (tid == 0){
    m = fmaxf(fmaxf(red[0], red[1]), fmaxf(red[2], red[3]));
    atomicMax(&Mo[b], ordkey(m));
  }
}

// fused: deterministic per-slice softmax-denom partials + atomic-free candidate
// collect (l > M - 1.75) via ballot compaction; one global atomicAdd per block.
__global__ __launch_bounds__(256) void Sampler_collectZ(const float* __restrict__ logits,
    const unsigned* __restrict__ Mo, float* __restrict__ Mb, float* __restrict__ Zp,
    unsigned* __restrict__ cnt, float* __restrict__ cval, unsigned* __restrict__ cidx){
  __shared__ float    sv[4][1024];
  __shared__ unsigned si[4][1024];
  __shared__ unsigned wcnt_s[4];
  __shared__ unsigned gbase_s;
  __shared__ float red[4];
  const int b = blockIdx.x >> 2, sl = blockIdx.x & 3;
  const int tid = threadIdx.x, wid = tid >> 6, lane = tid & 63;
  const float M = ordinv(Mo[b]);
  const float T = M - 1.75f;
  const int base = sl * 32000;
  const float4* row = (const float4*)(logits + (size_t)b * V_ + base);
  unsigned wcnt = 0;
  float z = 0.f;
  for (int i = tid; i < 8000; i += 256){     // 8000 = 31*256 + 64: tails wave-uniform
    float4 v = row[i];
    z += expf(v.x - M); z += expf(v.y - M);
    z += expf(v.z - M); z += expf(v.w - M);
    float vv[4] = {v.x, v.y, v.z, v.w};
    const unsigned idx0 = (unsigned)(base + i * 4);
#pragma unroll
    for (int j = 0; j < 4; ++j){
      bool q = vv[j] > T;
      unsigned long long mask = __ballot(q);
      if (q){
        unsigned slot = wcnt + (unsigned)__popcll(mask & ((1ull << lane) - 1ull));
        if (slot < 1024u){ sv[wid][slot] = vv[j]; si[wid][slot] = idx0 + j; }
      }
      wcnt += (unsigned)__popcll(mask);
    }
  }
  // deterministic Z partial (fixed shuffle order)
#pragma unroll
  for (int off = 32; off; off >>= 1) z += __shfl_down(z, off);
  if (lane == 0){ red[wid] = z; wcnt_s[wid] = wcnt < 1024u ? wcnt : 1024u; }
  __syncthreads();
  if (tid == 0){
    Zp[b * 4 + sl] = ((red[0] + red[1]) + red[2]) + red[3];
    if (sl == 0) Mb[b] = M;
    gbase_s = atomicAdd(&cnt[b], wcnt_s[0] + wcnt_s[1] + wcnt_s[2] + wcnt_s[3]);
  }
  __syncthreads();
  unsigned pre = gbase_s;
  for (int w = 0; w < 4; ++w){ if (w == wid) break; pre += wcnt_s[w]; }
  const unsigned myn = wcnt_s[wid];
  for (unsigned i = lane; i < myn; i += 64){
    unsigned pos = pre + i;
    if (pos < CAND_CAP){
      cval[b * CAND_CAP + pos] = sv[wid][i];
      cidx[b * CAND_CAP + pos] = si[wid][i];
    }
  }
}

// extract top-K (stable: value desc, index asc) by iterative argmax over candidates
__global__ __launch_bounds__(256) void Sampler_topk(const unsigned* __restrict__ cnt,
    const float* __restrict__ cval, const unsigned* __restrict__ cidx,
    const int* __restrict__ top_ks, float* __restrict__ tv, unsigned* __restrict__ ti,
    unsigned* __restrict__ kef){
  __shared__ unsigned long long keys[CAND_CAP];
  __shared__ unsigned long long red[4];
  const int b = blockIdx.x;
  const int tid = threadIdx.x;
  int n = (int)min(cnt[b], (unsigned)CAND_CAP);
  const int nr = (n + 255) & ~255;           // scan bound, multiple of 256
  for (int i = tid; i < nr; i += 256){
    unsigned long long kk = 0ull;
    if (i < n){
      unsigned o = ordkey(cval[b * CAND_CAP + i]);
      kk = ((unsigned long long)o << 32) | (unsigned long long)(0xFFFFFFFFu - cidx[b * CAND_CAP + i]);
    }
    keys[i] = kk;
  }
  __syncthreads();
  int K = top_ks[b];
  K = K < 1 ? 1 : (K > 63 ? 63 : K);
  K = K < n ? K : n;
  for (int k = 0; k < K; ++k){
    unsigned long long best = 0ull;
    for (int i = tid; i < nr; i += 256){
      unsigned long long xx = keys[i];
      best = xx > best ? xx : best;
    }
#pragma unroll
    for (int off = 32; off; off >>= 1){
      unsigned long long o = __shfl_down(best, off);
      best = o > best ? o : best;
    }
    if ((tid & 63) == 0) red[tid >> 6] = best;
    __syncthreads();
    {
      unsigned long long m01 = red[0] > red[1] ? red[0] : red[1];
      unsigned long long m23 = red[2] > red[3] ? red[2] : red[3];
      best = m01 > m23 ? m01 : m23;
    }
    for (int i = tid; i < nr; i += 256)
      if (keys[i] == best) keys[i] = 0ull;
    if (tid == 0){
      tv[b * 64 + k] = ordinv((unsigned)(best >> 32));
      ti[b * 64 + k] = 0xFFFFFFFFu - (unsigned)(best & 0xFFFFFFFFu);
    }
    __syncthreads();
  }
  if (tid == 0) kef[b] = (unsigned)K;
}

// top-p mask on sorted list + gumbel argmax -> token (written as float)
__global__ __launch_bounds__(64) void Sampler_sample(const float* __restrict__ tv,
    const unsigned* __restrict__ ti, const unsigned* __restrict__ kef,
    const float* __restrict__ Mb, const float* __restrict__ Zp,
    const float* __restrict__ top_ps, float* __restrict__ out_tok){
  const int b = blockIdx.x;
  const int k = threadIdx.x;
  const int K = (int)kef[b];
  const float M = Mb[b], tp = top_ps[b];
  const float Z = ((Zp[b * 4 + 0] + Zp[b * 4 + 1]) + Zp[b * 4 + 2]) + Zp[b * 4 + 3];
  float p = 0.f, lv = 0.f; unsigned iv = 0xFFFFFFFFu;
  if (k < K){
    lv = tv[b * 64 + k];
    iv = ti[b * 64 + k];
    p = expf(lv - M) / Z;
  }
  float incl = p;
#pragma unroll
  for (int off = 1; off < 64; off <<= 1){
    float t = __shfl_up(incl, off);
    if (k >= off) incl += t;
  }
  float excl = incl - p;
  float val = -3.4e38f; unsigned idx = 0xFFFFFFFFu;
  if (k < K && excl <= tp){
    val = lv + gumbel_at((uint32_t)b, iv);
    idx = iv;
  }
#pragma unroll
  for (int off = 32; off; off >>= 1){
    float ov = __shfl_down(val, off);
    unsigned oi = __shfl_down(idx, off);
    if (ov > val || (ov == val && oi < idx)){ val = ov; idx = oi; }
  }
  if (k == 0) out_tok[b] = (float)idx;
}

extern "C" void kernel_launch(void* const* d_in, const int* in_sizes, int n_in,
                              void* d_out, int out_size, void* d_ws, size_t ws_size,
                              hipStream_t stream){
  (void)in_sizes; (void)n_in; (void)out_size; (void)ws_size;
  const float* x      = (const float*)d_in[0];
  const float* emb    = (const float*)d_in[1];
  const float* ebias  = (const float*)d_in[2];
  const float* top_ps = (const float*)d_in[3];
  const int*   out_pos= (const int*)d_in[4];
  const int*   top_ks = (const int*)d_in[5];

  float* out    = (float*)d_out;       // [0..63] tokens (as float), then logits [64][V]
  float* logits = out + 64;

  // workspace layout
  unsigned short* hhi = (unsigned short*)d_ws;                    // packed A hi [64][2048] bf16
  unsigned short* hlo = hhi + (size_t)B_ * D_;                    // packed A lo
  char* wp = (char*)d_ws + (size_t)B_ * D_ * 4;                   // after 512KB
  unsigned* Mo   = (unsigned*)wp;          wp += 64 * 4;
  float*    Mb   = (float*)wp;             wp += 64 * 4;
  float*    Zp   = (float*)wp;             wp += 256 * 4;
  unsigned* cnt  = (unsigned*)wp;          wp += 64 * 4;
  unsigned* kef  = (unsigned*)wp;          wp += 64 * 4;
  float*    tv   = (float*)wp;             wp += 64 * 64 * 4;
  unsigned* ti   = (unsigned*)wp;          wp += 64 * 64 * 4;
  float*    cval = (float*)wp;             wp += (size_t)64 * CAND_CAP * 4;
  unsigned* cidx = (unsigned*)wp;          wp += (size_t)64 * CAND_CAP * 4;

  hipLaunchKernelGGL(Sampler_gather,   dim3((B_ * D_ + 255) / 256), dim3(256), 0, stream, x, out_pos, hhi, hlo, cnt, Mo);
  hipLaunchKernelGGL(Sampler_gemm,     dim3(NBLK), dim3(256), 0, stream, hhi, hlo, emb, ebias, logits);
  hipLaunchKernelGGL(Sampler_rowmax,   dim3(256), dim3(256), 0, stream, logits, Mo);
  hipLaunchKernelGGL(Sampler_collectZ, dim3(256), dim3(256), 0, stream, logits, Mo, Mb, Zp, cnt, cval, cidx);
  hipLaunchKernelGGL(Sampler_topk,     dim3(64), dim3(256), 0, stream, cnt, cval, cidx, top_ks, tv, ti, kef);
  hipLaunchKernelGGL(Sampler_sample,   dim3(64), dim3(64), 0, stream, tv, ti, kef, Mb, Zp, top_ps, out);
}

// Round 12
// 317.498 us; speedup vs baseline: 2.0495x; 2.0495x over previous
//
#include <hip/hip_runtime.h>
#include <cstdint>
#include <cstddef>

#define B_ 64
#define S_ 8
#define D_ 2048
#define V_ 128000
#define CAND_CAP 8192
#define NBLK 500            // V_/256 GEMM blocks

typedef __bf16 v8bf __attribute__((ext_vector_type(8)));
typedef float  v4f  __attribute__((ext_vector_type(4)));

#define GLOBAL_AS __attribute__((address_space(1)))
#define LDS_AS    __attribute__((address_space(3)))

__device__ __forceinline__ void gload_lds16(const float* g, float* l){
  __builtin_amdgcn_global_load_lds((const GLOBAL_AS uint32_t*)g, (LDS_AS uint32_t*)l, 16, 0, 0);
}

// ---------------- threefry2x32 (JAX-compatible) ----------------
__device__ __forceinline__ uint32_t rotl32(uint32_t x, int r){ return (x << r) | (x >> (32 - r)); }
__device__ __forceinline__ void tfround(uint32_t& x0, uint32_t& x1, int r){
  x0 += x1; x1 = rotl32(x1, r); x1 ^= x0;
}
__device__ __forceinline__ void threefry2x32(uint32_t k0, uint32_t k1, uint32_t c0, uint32_t c1,
                                             uint32_t& o0, uint32_t& o1){
  uint32_t ks2 = k0 ^ k1 ^ 0x1BD11BDAu;
  uint32_t x0 = c0 + k0, x1 = c1 + k1;
  tfround(x0,x1,13); tfround(x0,x1,15); tfround(x0,x1,26); tfround(x0,x1,6);
  x0 += k1; x1 += ks2 + 1u;
  tfround(x0,x1,17); tfround(x0,x1,29); tfround(x0,x1,16); tfround(x0,x1,24);
  x0 += ks2; x1 += k0 + 2u;
  tfround(x0,x1,13); tfround(x0,x1,15); tfround(x0,x1,26); tfround(x0,x1,6);
  x0 += k0; x1 += k1 + 3u;
  tfround(x0,x1,17); tfround(x0,x1,29); tfround(x0,x1,16); tfround(x0,x1,24);
  x0 += k1; x1 += ks2 + 4u;
  tfround(x0,x1,13); tfround(x0,x1,15); tfround(x0,x1,26); tfround(x0,x1,6);
  x0 += ks2; x1 += k0 + 5u;
  o0 = x0; o1 = x1;
}

#define JAX_PARTITIONABLE 1

__device__ __forceinline__ float gumbel_at(uint32_t b, uint32_t v){
  uint32_t j = b * (uint32_t)V_ + v;
  uint32_t bits;
#if JAX_PARTITIONABLE
  uint32_t o0, o1; threefry2x32(0u, 42u, 0u, j, o0, o1);
  bits = o0 ^ o1;
#else
  const uint32_t HALF = 4096000u;  // B*V/2
  uint32_t o0, o1;
  if (j < HALF){ threefry2x32(0u, 42u, j, j + HALF, o0, o1); bits = o0; }
  else        { threefry2x32(0u, 42u, j - HALF, j, o0, o1); bits = o1; }
#endif
  uint32_t fb = (bits >> 9) | 0x3F800000u;
  float f = __uint_as_float(fb) - 1.0f;
  const float TINY = 1.17549435e-38f;
  float u = fmaxf(TINY, f + TINY);
  return -logf(-logf(u));
}

__device__ __forceinline__ unsigned ordkey(float f){
  unsigned u = __float_as_uint(f);
  return (u & 0x80000000u) ? ~u : (u | 0x80000000u);
}
__device__ __forceinline__ float ordinv(unsigned o){
  unsigned u = (o & 0x80000000u) ? (o & 0x7FFFFFFFu) : ~o;
  return __uint_as_float(u);
}

__device__ __forceinline__ v8bf ld_bf8(const unsigned short* p){
  uint4 u = *reinterpret_cast<const uint4*>(p);
  return __builtin_bit_cast(v8bf, u);
}

// ---------------- kernels ----------------

// gather h at out_pos, split fp32 -> bf16 hi/lo in FRAGMENT-PACKED layout:
// Apk[(((s*4 + mi)*64) + kg*16 + r16)*8 + j], s = k>>5, kg=(k>>3)&3, j=k&7, mi=b>>4, r16=b&15
__global__ __launch_bounds__(256) void Sampler_gather(const float* __restrict__ x,
    const int* __restrict__ out_pos, unsigned short* __restrict__ hhi,
    unsigned short* __restrict__ hlo, unsigned* __restrict__ cnt){
  const int pos = out_pos[0];
  int i = blockIdx.x * 256 + threadIdx.x;
  if (i < B_ * D_){
    int bq = i >> 11;          // b
    int kq = i & 2047;         // k
    float v = x[((size_t)bq * S_ + pos) * D_ + kq];
    __bf16 hb = (__bf16)v;
    float hf = (float)hb;
    __bf16 lb = (__bf16)(v - hf);
    int s  = kq >> 5;
    int kg = (kq >> 3) & 3;
    int j  = kq & 7;
    int mi = bq >> 4;
    int r16 = bq & 15;
    int idx = (((s * 4 + mi) * 64) + kg * 16 + r16) * 8 + j;
    hhi[idx] = __builtin_bit_cast(unsigned short, hb);
    hlo[idx] = __builtin_bit_cast(unsigned short, lb);
  }
  if (i < 64) cnt[i] = 0;
}

// Split-bf16 MFMA GEMM with LDS-staged B (R6 structure, byte-identical loop)
// + light row-max partial epilogue (pm[NBLK][64], no expf).
__global__ __launch_bounds__(256, 2) void Sampler_gemm(
    const unsigned short* __restrict__ hhi,  // packed A hi
    const unsigned short* __restrict__ hlo,  // packed A lo
    const float* __restrict__ emb,           // [V_][D_]
    const float* __restrict__ bias,          // [V_]
    float* __restrict__ out,                 // [64][V_]
    float* __restrict__ pm)                  // [NBLK][64] per-block row max
{
  __shared__ float Bs[2][256 * 32];          // 2 x 32 KB
  __shared__ float mW[4][64];                // 1 KB epilogue reduce
  const int tid  = threadIdx.x;
  const int wid  = tid >> 6;
  const int lane = tid & 63;
  const int r16  = lane & 15;
  const int kg   = lane >> 4;                // 0..3
  const int vbase = (blockIdx.x << 8) + (wid << 6);

  // staging constants: thread t stages dst bytes t*16 + p*4096 (p=0..7)
  const int srow = tid >> 3;                 // row within 32-row p-group
  const int hsrc = (tid & 7) ^ (srow & 7);   // inverse-swizzled source granule
  const float* sbase = emb + (size_t)((blockIdx.x << 8) + srow) * D_ + hsrc * 4;

  // read constants: phys granules for this lane's k-slice (row&7 == r16&7)
  const int h0 = ((2 * kg)     ^ (r16 & 7)) * 4;  // in floats
  const int h1 = ((2 * kg + 1) ^ (r16 & 7)) * 4;

  v4f acc[4][4];
#pragma unroll
  for (int mi = 0; mi < 4; ++mi)
#pragma unroll
    for (int ni = 0; ni < 4; ++ni) acc[mi][ni] = (v4f){0.f, 0.f, 0.f, 0.f};

  const unsigned short* hhb = hhi + lane * 8;
  const unsigned short* hlb = hlo + lane * 8;

  // prologue: stage chunk 0
#pragma unroll
  for (int p = 0; p < 8; ++p)
    gload_lds16(sbase + (size_t)p * 32 * D_, &Bs[0][tid * 4 + p * 1024]);
  __syncthreads();

#pragma unroll 1
  for (int c = 0; c < 64; ++c){
    const int cur = c & 1;

    // A fragments (L2-resident, coalesced packed layout)
    v8bf ah[4], al[4];
#pragma unroll
    for (int mi = 0; mi < 4; ++mi){
      const int fo = (c * 4 + mi) * 512;
      ah[mi] = ld_bf8(hhb + fo);
      al[mi] = ld_bf8(hlb + fo);
    }

    // stage next chunk into the other buffer
    if (c + 1 < 64){
#pragma unroll
      for (int p = 0; p < 8; ++p)
        gload_lds16(sbase + (size_t)p * 32 * D_ + (c * 32 + 32),
                    &Bs[cur ^ 1][tid * 4 + p * 1024]);
    }

    // compute from current buffer
#pragma unroll
    for (int ni = 0; ni < 4; ++ni){
      const int r = (wid << 6) + (ni << 4) + r16;
      const float* bp = &Bs[cur][r * 32];
      float4 b0 = *(const float4*)(bp + h0);   // k = 8kg .. +3
      float4 b1 = *(const float4*)(bp + h1);   // k = 8kg+4 .. +7
      float xf[8] = { b0.x, b0.y, b0.z, b0.w, b1.x, b1.y, b1.z, b1.w };
      v8bf bh, bl;
#pragma unroll
      for (int j = 0; j < 8; ++j){
        float v = xf[j];
        __bf16 hb = (__bf16)v;
        float hf = (float)hb;
        bh[j] = hb;
        bl[j] = (__bf16)(v - hf);
      }
#pragma unroll
      for (int mi = 0; mi < 4; ++mi){
        acc[mi][ni] = __builtin_amdgcn_mfma_f32_16x16x32_bf16(ah[mi], bh, acc[mi][ni], 0, 0, 0);
        acc[mi][ni] = __builtin_amdgcn_mfma_f32_16x16x32_bf16(al[mi], bh, acc[mi][ni], 0, 0, 0);
        acc[mi][ni] = __builtin_amdgcn_mfma_f32_16x16x32_bf16(ah[mi], bl, acc[mi][ni], 0, 0, 0);
      }
    }
    __syncthreads();   // drains vmcnt(0): next buffer complete; LDS WAR safe
  }

  // epilogue: + bias, store, and per-block row-max partials (no expf)
  float mloc[4][4];
#pragma unroll
  for (int mi = 0; mi < 4; ++mi)
#pragma unroll
    for (int r = 0; r < 4; ++r) mloc[mi][r] = -3.4e38f;
#pragma unroll
  for (int ni = 0; ni < 4; ++ni){
    const int v = vbase + 16 * ni + r16;
    const float bv = bias[v];
#pragma unroll
    for (int mi = 0; mi < 4; ++mi){
#pragma unroll
      for (int r = 0; r < 4; ++r){
        const int b = 16 * mi + 4 * kg + r;
        float val = acc[mi][ni][r] + bv;
        out[(size_t)b * V_ + v] = val;
        mloc[mi][r] = fmaxf(mloc[mi][r], val);
      }
    }
  }
  // reduce across the 16 r16-lanes of each kg group
#pragma unroll
  for (int off = 1; off < 16; off <<= 1)
#pragma unroll
    for (int mi = 0; mi < 4; ++mi)
#pragma unroll
      for (int r = 0; r < 4; ++r)
        mloc[mi][r] = fmaxf(mloc[mi][r], __shfl_xor(mloc[mi][r], off));
  if (r16 == 0){
#pragma unroll
    for (int mi = 0; mi < 4; ++mi)
#pragma unroll
      for (int r = 0; r < 4; ++r)
        mW[wid][16 * mi + 4 * kg + r] = mloc[mi][r];
  }
  __syncthreads();
  if (tid < 64){
    float m = fmaxf(fmaxf(mW[0][tid], mW[1][tid]), fmaxf(mW[2][tid], mW[3][tid]));
    pm[blockIdx.x * 64 + tid] = m;
  }
}

// combine per-block max partials -> Mb
__global__ __launch_bounds__(256) void Sampler_combine(const float* __restrict__ pm,
    float* __restrict__ Mb){
  __shared__ float red[4];
  const int row = blockIdx.x;
  const int tid = threadIdx.x;
  float m = -3.4e38f;
  for (int p = tid; p < NBLK; p += 256) m = fmaxf(m, pm[p * 64 + row]);
#pragma unroll
  for (int off = 32; off; off >>= 1) m = fmaxf(m, __shfl_down(m, off));
  if ((tid & 63) == 0) red[tid >> 6] = m;
  __syncthreads();
  if (tid == 0)
    Mb[row] = fmaxf(fmaxf(red[0], red[1]), fmaxf(red[2], red[3]));
}

// fused: deterministic per-slice softmax-denom partials + atomic-free candidate
// collect (l > M - 1.75) via ballot compaction; 8 slices per row (512 blocks).
__global__ __launch_bounds__(256) void Sampler_collectZ(const float* __restrict__ logits,
    const float* __restrict__ Mb, float* __restrict__ Zp,
    unsigned* __restrict__ cnt, float* __restrict__ cval, unsigned* __restrict__ cidx){
  __shared__ float    sv[4][1024];
  __shared__ unsigned si[4][1024];
  __shared__ unsigned wcnt_s[4];
  __shared__ unsigned gbase_s;
  __shared__ float red[4];
  const int b = blockIdx.x >> 3, sl = blockIdx.x & 7;
  const int tid = threadIdx.x, wid = tid >> 6, lane = tid & 63;
  const float M = Mb[b];
  const float T = M - 1.75f;
  const int base = sl * 16000;
  const float4* row = (const float4*)(logits + (size_t)b * V_ + base);
  unsigned wcnt = 0;
  float z = 0.f;
  for (int i = tid; i < 4000; i += 256){
    float4 v = row[i];
    z += expf(v.x - M); z += expf(v.y - M);
    z += expf(v.z - M); z += expf(v.w - M);
    float vv[4] = {v.x, v.y, v.z, v.w};
    const unsigned idx0 = (unsigned)(base + i * 4);
#pragma unroll
    for (int j = 0; j < 4; ++j){
      bool q = vv[j] > T;
      unsigned long long mask = __ballot(q);
      if (q){
        unsigned slot = wcnt + (unsigned)__popcll(mask & ((1ull << lane) - 1ull));
        if (slot < 1024u){ sv[wid][slot] = vv[j]; si[wid][slot] = idx0 + j; }
      }
      wcnt += (unsigned)__popcll(mask);
    }
  }
  // deterministic Z partial (fixed shuffle order)
#pragma unroll
  for (int off = 32; off; off >>= 1) z += __shfl_down(z, off);
  if (lane == 0){ red[wid] = z; wcnt_s[wid] = wcnt < 1024u ? wcnt : 1024u; }
  __syncthreads();
  if (tid == 0){
    Zp[b * 8 + sl] = ((red[0] + red[1]) + red[2]) + red[3];
    gbase_s = atomicAdd(&cnt[b], wcnt_s[0] + wcnt_s[1] + wcnt_s[2] + wcnt_s[3]);
  }
  __syncthreads();
  unsigned pre = gbase_s;
  for (int w = 0; w < 4; ++w){ if (w == wid) break; pre += wcnt_s[w]; }
  const unsigned myn = wcnt_s[wid];
  for (unsigned i = lane; i < myn; i += 64){
    unsigned pos = pre + i;
    if (pos < CAND_CAP){
      cval[b * CAND_CAP + pos] = sv[wid][i];
      cidx[b * CAND_CAP + pos] = si[wid][i];
    }
  }
}

// extract top-K (stable: value desc, index asc) by iterative argmax over candidates
__global__ __launch_bounds__(512) void Sampler_topk(const unsigned* __restrict__ cnt,
    const float* __restrict__ cval, const unsigned* __restrict__ cidx,
    const int* __restrict__ top_ks, float* __restrict__ tv, unsigned* __restrict__ ti,
    unsigned* __restrict__ kef){
  __shared__ unsigned long long keys[CAND_CAP];
  __shared__ unsigned long long red[8];
  const int b = blockIdx.x;
  const int tid = threadIdx.x;
  int n = (int)min(cnt[b], (unsigned)CAND_CAP);
  const int nr = (n + 511) & ~511;           // scan bound, multiple of 512
  for (int i = tid; i < nr; i += 512){
    unsigned long long kk = 0ull;
    if (i < n){
      unsigned o = ordkey(cval[b * CAND_CAP + i]);
      kk = ((unsigned long long)o << 32) | (unsigned long long)(0xFFFFFFFFu - cidx[b * CAND_CAP + i]);
    }
    keys[i] = kk;
  }
  __syncthreads();
  int K = top_ks[b];
  K = K < 1 ? 1 : (K > 63 ? 63 : K);
  K = K < n ? K : n;
  for (int k = 0; k < K; ++k){
    unsigned long long best = 0ull;
    for (int i = tid; i < nr; i += 512){
      unsigned long long xx = keys[i];
      best = xx > best ? xx : best;
    }
#pragma unroll
    for (int off = 32; off; off >>= 1){
      unsigned long long o = __shfl_down(best, off);
      best = o > best ? o : best;
    }
    if ((tid & 63) == 0) red[tid >> 6] = best;
    __syncthreads();
    {
      unsigned long long m01 = red[0] > red[1] ? red[0] : red[1];
      unsigned long long m23 = red[2] > red[3] ? red[2] : red[3];
      unsigned long long m45 = red[4] > red[5] ? red[4] : red[5];
      unsigned long long m67 = red[6] > red[7] ? red[6] : red[7];
      unsigned long long a = m01 > m23 ? m01 : m23;
      unsigned long long c2 = m45 > m67 ? m45 : m67;
      best = a > c2 ? a : c2;
    }
    for (int i = tid; i < nr; i += 512)
      if (keys[i] == best) keys[i] = 0ull;
    if (tid == 0){
      tv[b * 64 + k] = ordinv((unsigned)(best >> 32));
      ti[b * 64 + k] = 0xFFFFFFFFu - (unsigned)(best & 0xFFFFFFFFu);
    }
    __syncthreads();
  }
  if (tid == 0) kef[b] = (unsigned)K;
}

// top-p mask on sorted list + gumbel argmax -> token (written as float)
__global__ __launch_bounds__(64) void Sampler_sample(const float* __restrict__ tv,
    const unsigned* __restrict__ ti, const unsigned* __restrict__ kef,
    const float* __restrict__ Mb, const float* __restrict__ Zp,
    const float* __restrict__ top_ps, float* __restrict__ out_tok){
  const int b = blockIdx.x;
  const int k = threadIdx.x;
  const int K = (int)kef[b];
  const float M = Mb[b], tp = top_ps[b];
  float Z = 0.f;
#pragma unroll
  for (int s = 0; s < 8; ++s) Z += Zp[b * 8 + s];
  float p = 0.f, lv = 0.f; unsigned iv = 0xFFFFFFFFu;
  if (k < K){
    lv = tv[b * 64 + k];
    iv = ti[b * 64 + k];
    p = expf(lv - M) / Z;
  }
  float incl = p;
#pragma unroll
  for (int off = 1; off < 64; off <<= 1){
    float t = __shfl_up(incl, off);
    if (k >= off) incl += t;
  }
  float excl = incl - p;
  float val = -3.4e38f; unsigned idx = 0xFFFFFFFFu;
  if (k < K && excl <= tp){
    val = lv + gumbel_at((uint32_t)b, iv);
    idx = iv;
  }
#pragma unroll
  for (int off = 32; off; off >>= 1){
    float ov = __shfl_down(val, off);
    unsigned oi = __shfl_down(idx, off);
    if (ov > val || (ov == val && oi < idx)){ val = ov; idx = oi; }
  }
  if (k == 0) out_tok[b] = (float)idx;
}

extern "C" void kernel_launch(void* const* d_in, const int* in_sizes, int n_in,
                              void* d_out, int out_size, void* d_ws, size_t ws_size,
                              hipStream_t stream){
  (void)in_sizes; (void)n_in; (void)out_size; (void)ws_size;
  const float* x      = (const float*)d_in[0];
  const float* emb    = (const float*)d_in[1];
  const float* ebias  = (const float*)d_in[2];
  const float* top_ps = (const float*)d_in[3];
  const int*   out_pos= (const int*)d_in[4];
  const int*   top_ks = (const int*)d_in[5];

  float* out    = (float*)d_out;       // [0..63] tokens (as float), then logits [64][V]
  float* logits = out + 64;

  // workspace layout
  unsigned short* hhi = (unsigned short*)d_ws;                    // packed A hi [64][2048] bf16
  unsigned short* hlo = hhi + (size_t)B_ * D_;                    // packed A lo
  char* wp = (char*)d_ws + (size_t)B_ * D_ * 4;                   // after 512KB
  float*    pm   = (float*)wp;             wp += (size_t)NBLK * 64 * 4;
  float*    Mb   = (float*)wp;             wp += 64 * 4;
  float*    Zp   = (float*)wp;             wp += 64 * 8 * 4;
  unsigned* cnt  = (unsigned*)wp;          wp += 64 * 4;
  unsigned* kef  = (unsigned*)wp;          wp += 64 * 4;
  float*    tv   = (float*)wp;             wp += 64 * 64 * 4;
  unsigned* ti   = (unsigned*)wp;          wp += 64 * 64 * 4;
  float*    cval = (float*)wp;             wp += (size_t)64 * CAND_CAP * 4;
  unsigned* cidx = (unsigned*)wp;          wp += (size_t)64 * CAND_CAP * 4;

  hipLaunchKernelGGL(Sampler_gather,   dim3((B_ * D_ + 255) / 256), dim3(256), 0, stream, x, out_pos, hhi, hlo, cnt);
  hipLaunchKernelGGL(Sampler_gemm,     dim3(NBLK), dim3(256), 0, stream, hhi, hlo, emb, ebias, logits, pm);
  hipLaunchKernelGGL(Sampler_combine,  dim3(64), dim3(256), 0, stream, pm, Mb);
  hipLaunchKernelGGL(Sampler_collectZ, dim3(512), dim3(256), 0, stream, logits, Mb, Zp, cnt, cval, cidx);
  hipLaunchKernelGGL(Sampler_topk,     dim3(64), dim3(512), 0, stream, cnt, cval, cidx, top_ks, tv, ti, kef);
  hipLaunchKernelGGL(Sampler_sample,   dim3(64), dim3(64), 0, stream, tv, ti, kef, Mb, Zp, top_ps, out);
}

// Round 13
// 281.679 us; speedup vs baseline: 2.3101x; 1.1272x over previous
//
#include <hip/hip_runtime.h>
#include <cstdint>
#include <cstddef>

#define B_ 64
#define S_ 8
#define D_ 2048
#define V_ 128000
#define CAND_CAP 8192
#define NBLK 500            // V_/256 GEMM blocks

typedef __bf16 v8bf __attribute__((ext_vector_type(8)));
typedef float  v4f  __attribute__((ext_vector_type(4)));

#define GLOBAL_AS __attribute__((address_space(1)))
#define LDS_AS    __attribute__((address_space(3)))

// NT (non-temporal) cache policy for read-once streams: CPol::NT = 2
__device__ __forceinline__ void gload_lds16_nt(const float* g, float* l){
  __builtin_amdgcn_global_load_lds((const GLOBAL_AS uint32_t*)g, (LDS_AS uint32_t*)l, 16, 0, 2);
}

// ---------------- threefry2x32 (JAX-compatible) ----------------
__device__ __forceinline__ uint32_t rotl32(uint32_t x, int r){ return (x << r) | (x >> (32 - r)); }
__device__ __forceinline__ void tfround(uint32_t& x0, uint32_t& x1, int r){
  x0 += x1; x1 = rotl32(x1, r); x1 ^= x0;
}
__device__ __forceinline__ void threefry2x32(uint32_t k0, uint32_t k1, uint32_t c0, uint32_t c1,
                                             uint32_t& o0, uint32_t& o1){
  uint32_t ks2 = k0 ^ k1 ^ 0x1BD11BDAu;
  uint32_t x0 = c0 + k0, x1 = c1 + k1;
  tfround(x0,x1,13); tfround(x0,x1,15); tfround(x0,x1,26); tfround(x0,x1,6);
  x0 += k1; x1 += ks2 + 1u;
  tfround(x0,x1,17); tfround(x0,x1,29); tfround(x0,x1,16); tfround(x0,x1,24);
  x0 += ks2; x1 += k0 + 2u;
  tfround(x0,x1,13); tfround(x0,x1,15); tfround(x0,x1,26); tfround(x0,x1,6);
  x0 += k0; x1 += k1 + 3u;
  tfround(x0,x1,17); tfround(x0,x1,29); tfround(x0,x1,16); tfround(x0,x1,24);
  x0 += k1; x1 += ks2 + 4u;
  tfround(x0,x1,13); tfround(x0,x1,15); tfround(x0,x1,26); tfround(x0,x1,6);
  x0 += ks2; x1 += k0 + 5u;
  o0 = x0; o1 = x1;
}

#define JAX_PARTITIONABLE 1

__device__ __forceinline__ float gumbel_at(uint32_t b, uint32_t v){
  uint32_t j = b * (uint32_t)V_ + v;
  uint32_t bits;
#if JAX_PARTITIONABLE
  uint32_t o0, o1; threefry2x32(0u, 42u, 0u, j, o0, o1);
  bits = o0 ^ o1;
#else
  const uint32_t HALF = 4096000u;  // B*V/2
  uint32_t o0, o1;
  if (j < HALF){ threefry2x32(0u, 42u, j, j + HALF, o0, o1); bits = o0; }
  else        { threefry2x32(0u, 42u, j - HALF, j, o0, o1); bits = o1; }
#endif
  uint32_t fb = (bits >> 9) | 0x3F800000u;
  float f = __uint_as_float(fb) - 1.0f;
  const float TINY = 1.17549435e-38f;
  float u = fmaxf(TINY, f + TINY);
  return -logf(-logf(u));
}

__device__ __forceinline__ unsigned ordkey(float f){
  unsigned u = __float_as_uint(f);
  return (u & 0x80000000u) ? ~u : (u | 0x80000000u);
}
__device__ __forceinline__ float ordinv(unsigned o){
  unsigned u = (o & 0x80000000u) ? (o & 0x7FFFFFFFu) : ~o;
  return __uint_as_float(u);
}

__device__ __forceinline__ v8bf ld_bf8(const unsigned short* p){
  uint4 u = *reinterpret_cast<const uint4*>(p);
  return __builtin_bit_cast(v8bf, u);
}

// ---------------- kernels ----------------

// gather h at out_pos, split fp32 -> bf16 hi/lo in FRAGMENT-PACKED layout:
// Apk[(((s*4 + mi)*64) + kg*16 + r16)*8 + j], s = k>>5, kg=(k>>3)&3, j=k&7, mi=b>>4, r16=b&15
__global__ __launch_bounds__(256) void Sampler_gather(const float* __restrict__ x,
    const int* __restrict__ out_pos, unsigned short* __restrict__ hhi,
    unsigned short* __restrict__ hlo, unsigned* __restrict__ cnt){
  const int pos = out_pos[0];
  int i = blockIdx.x * 256 + threadIdx.x;
  if (i < B_ * D_){
    int bq = i >> 11;          // b
    int kq = i & 2047;         // k
    float v = x[((size_t)bq * S_ + pos) * D_ + kq];
    __bf16 hb = (__bf16)v;
    float hf = (float)hb;
    __bf16 lb = (__bf16)(v - hf);
    int s  = kq >> 5;
    int kg = (kq >> 3) & 3;
    int j  = kq & 7;
    int mi = bq >> 4;
    int r16 = bq & 15;
    int idx = (((s * 4 + mi) * 64) + kg * 16 + r16) * 8 + j;
    hhi[idx] = __builtin_bit_cast(unsigned short, hb);
    hlo[idx] = __builtin_bit_cast(unsigned short, lb);
  }
  if (i < 64) cnt[i] = 0;
}

// Split-bf16 MFMA GEMM with LDS-staged B (R6/R12 structure; NT policy on the
// read-once emb stream) + light row-max partial epilogue (pm[NBLK][64]).
__global__ __launch_bounds__(256, 2) void Sampler_gemm(
    const unsigned short* __restrict__ hhi,  // packed A hi
    const unsigned short* __restrict__ hlo,  // packed A lo
    const float* __restrict__ emb,           // [V_][D_]
    const float* __restrict__ bias,          // [V_]
    float* __restrict__ out,                 // [64][V_]
    float* __restrict__ pm)                  // [NBLK][64] per-block row max
{
  __shared__ float Bs[2][256 * 32];          // 2 x 32 KB
  __shared__ float mW[4][64];                // 1 KB epilogue reduce
  const int tid  = threadIdx.x;
  const int wid  = tid >> 6;
  const int lane = tid & 63;
  const int r16  = lane & 15;
  const int kg   = lane >> 4;                // 0..3
  const int vbase = (blockIdx.x << 8) + (wid << 6);

  // staging constants: thread t stages dst bytes t*16 + p*4096 (p=0..7)
  const int srow = tid >> 3;                 // row within 32-row p-group
  const int hsrc = (tid & 7) ^ (srow & 7);   // inverse-swizzled source granule
  const float* sbase = emb + (size_t)((blockIdx.x << 8) + srow) * D_ + hsrc * 4;

  // read constants: phys granules for this lane's k-slice (row&7 == r16&7)
  const int h0 = ((2 * kg)     ^ (r16 & 7)) * 4;  // in floats
  const int h1 = ((2 * kg + 1) ^ (r16 & 7)) * 4;

  v4f acc[4][4];
#pragma unroll
  for (int mi = 0; mi < 4; ++mi)
#pragma unroll
    for (int ni = 0; ni < 4; ++ni) acc[mi][ni] = (v4f){0.f, 0.f, 0.f, 0.f};

  const unsigned short* hhb = hhi + lane * 8;
  const unsigned short* hlb = hlo + lane * 8;

  // prologue: stage chunk 0
#pragma unroll
  for (int p = 0; p < 8; ++p)
    gload_lds16_nt(sbase + (size_t)p * 32 * D_, &Bs[0][tid * 4 + p * 1024]);
  __syncthreads();

#pragma unroll 1
  for (int c = 0; c < 64; ++c){
    const int cur = c & 1;

    // A fragments (L2-resident, coalesced packed layout; cacheable)
    v8bf ah[4], al[4];
#pragma unroll
    for (int mi = 0; mi < 4; ++mi){
      const int fo = (c * 4 + mi) * 512;
      ah[mi] = ld_bf8(hhb + fo);
      al[mi] = ld_bf8(hlb + fo);
    }

    // stage next chunk into the other buffer (NT: read-once stream)
    if (c + 1 < 64){
#pragma unroll
      for (int p = 0; p < 8; ++p)
        gload_lds16_nt(sbase + (size_t)p * 32 * D_ + (c * 32 + 32),
                       &Bs[cur ^ 1][tid * 4 + p * 1024]);
    }

    // compute from current buffer
#pragma unroll
    for (int ni = 0; ni < 4; ++ni){
      const int r = (wid << 6) + (ni << 4) + r16;
      const float* bp = &Bs[cur][r * 32];
      float4 b0 = *(const float4*)(bp + h0);   // k = 8kg .. +3
      float4 b1 = *(const float4*)(bp + h1);   // k = 8kg+4 .. +7
      float xf[8] = { b0.x, b0.y, b0.z, b0.w, b1.x, b1.y, b1.z, b1.w };
      v8bf bh, bl;
#pragma unroll
      for (int j = 0; j < 8; ++j){
        float v = xf[j];
        __bf16 hb = (__bf16)v;
        float hf = (float)hb;
        bh[j] = hb;
        bl[j] = (__bf16)(v - hf);
      }
#pragma unroll
      for (int mi = 0; mi < 4; ++mi){
        acc[mi][ni] = __builtin_amdgcn_mfma_f32_16x16x32_bf16(ah[mi], bh, acc[mi][ni], 0, 0, 0);
        acc[mi][ni] = __builtin_amdgcn_mfma_f32_16x16x32_bf16(al[mi], bh, acc[mi][ni], 0, 0, 0);
        acc[mi][ni] = __builtin_amdgcn_mfma_f32_16x16x32_bf16(ah[mi], bl, acc[mi][ni], 0, 0, 0);
      }
    }
    __syncthreads();   // drains vmcnt(0): next buffer complete; LDS WAR safe
  }

  // epilogue: + bias, store, and per-block row-max partials (no expf)
  float mloc[4][4];
#pragma unroll
  for (int mi = 0; mi < 4; ++mi)
#pragma unroll
    for (int r = 0; r < 4; ++r) mloc[mi][r] = -3.4e38f;
#pragma unroll
  for (int ni = 0; ni < 4; ++ni){
    const int v = vbase + 16 * ni + r16;
    const float bv = bias[v];
#pragma unroll
    for (int mi = 0; mi < 4; ++mi){
#pragma unroll
      for (int r = 0; r < 4; ++r){
        const int b = 16 * mi + 4 * kg + r;
        float val = acc[mi][ni][r] + bv;
        out[(size_t)b * V_ + v] = val;
        mloc[mi][r] = fmaxf(mloc[mi][r], val);
      }
    }
  }
  // reduce across the 16 r16-lanes of each kg group
#pragma unroll
  for (int off = 1; off < 16; off <<= 1)
#pragma unroll
    for (int mi = 0; mi < 4; ++mi)
#pragma unroll
      for (int r = 0; r < 4; ++r)
        mloc[mi][r] = fmaxf(mloc[mi][r], __shfl_xor(mloc[mi][r], off));
  if (r16 == 0){
#pragma unroll
    for (int mi = 0; mi < 4; ++mi)
#pragma unroll
      for (int r = 0; r < 4; ++r)
        mW[wid][16 * mi + 4 * kg + r] = mloc[mi][r];
  }
  __syncthreads();
  if (tid < 64){
    float m = fmaxf(fmaxf(mW[0][tid], mW[1][tid]), fmaxf(mW[2][tid], mW[3][tid]));
    pm[blockIdx.x * 64 + tid] = m;
  }
}

// fused: inline pm-reduce (global row max, deterministic tree) + per-slice
// softmax-denom partials + atomic-free candidate collect (l > M - 1.75).
// 16 slices per row -> 1024 blocks (4 blocks/CU).
__global__ __launch_bounds__(256) void Sampler_collectZ(const float* __restrict__ logits,
    const float* __restrict__ pm, float* __restrict__ Mb, float* __restrict__ Zp,
    unsigned* __restrict__ cnt, float* __restrict__ cval, unsigned* __restrict__ cidx){
  __shared__ float    sv[4][1024];
  __shared__ unsigned si[4][1024];
  __shared__ unsigned wcnt_s[4];
  __shared__ unsigned gbase_s;
  __shared__ float red[4];
  __shared__ float sM;
  const int b = blockIdx.x >> 4, sl = blockIdx.x & 15;
  const int tid = threadIdx.x, wid = tid >> 6, lane = tid & 63;

  // inline combine: global row max from pm[NBLK][64] (same tree in all blocks)
  {
    float m = -3.4e38f;
    if (tid < NBLK)       m = pm[tid * 64 + b];
    if (tid + 256 < NBLK) m = fmaxf(m, pm[(tid + 256) * 64 + b]);
#pragma unroll
    for (int off = 32; off; off >>= 1) m = fmaxf(m, __shfl_down(m, off));
    if ((tid & 63) == 0) red[wid] = m;
    __syncthreads();
    if (tid == 0){
      sM = fmaxf(fmaxf(red[0], red[1]), fmaxf(red[2], red[3]));
      if (sl == 0) Mb[b] = sM;
    }
    __syncthreads();
  }
  const float M = sM;
  const float T = M - 1.75f;
  const int base = sl * 8000;
  const float4* row = (const float4*)(logits + (size_t)b * V_ + base);
  unsigned wcnt = 0;
  float z = 0.f;
  for (int i = tid; i < 2000; i += 256){
    float4 v = row[i];
    z += expf(v.x - M); z += expf(v.y - M);
    z += expf(v.z - M); z += expf(v.w - M);
    float vv[4] = {v.x, v.y, v.z, v.w};
    const unsigned idx0 = (unsigned)(base + i * 4);
#pragma unroll
    for (int j = 0; j < 4; ++j){
      bool q = vv[j] > T;
      unsigned long long mask = __ballot(q);
      if (q){
        unsigned slot = wcnt + (unsigned)__popcll(mask & ((1ull << lane) - 1ull));
        if (slot < 1024u){ sv[wid][slot] = vv[j]; si[wid][slot] = idx0 + j; }
      }
      wcnt += (unsigned)__popcll(mask);
    }
  }
  // deterministic Z partial (fixed shuffle order)
#pragma unroll
  for (int off = 32; off; off >>= 1) z += __shfl_down(z, off);
  __syncthreads();
  if (lane == 0){ red[wid] = z; wcnt_s[wid] = wcnt < 1024u ? wcnt : 1024u; }
  __syncthreads();
  if (tid == 0){
    Zp[b * 16 + sl] = ((red[0] + red[1]) + red[2]) + red[3];
    gbase_s = atomicAdd(&cnt[b], wcnt_s[0] + wcnt_s[1] + wcnt_s[2] + wcnt_s[3]);
  }
  __syncthreads();
  unsigned pre = gbase_s;
  for (int w = 0; w < 4; ++w){ if (w == wid) break; pre += wcnt_s[w]; }
  const unsigned myn = wcnt_s[wid];
  for (unsigned i = lane; i < myn; i += 64){
    unsigned pos = pre + i;
    if (pos < CAND_CAP){
      cval[b * CAND_CAP + pos] = sv[wid][i];
      cidx[b * CAND_CAP + pos] = si[wid][i];
    }
  }
}

// extract top-K (stable: value desc, index asc) by iterative argmax over candidates
__global__ __launch_bounds__(512) void Sampler_topk(const unsigned* __restrict__ cnt,
    const float* __restrict__ cval, const unsigned* __restrict__ cidx,
    const int* __restrict__ top_ks, float* __restrict__ tv, unsigned* __restrict__ ti,
    unsigned* __restrict__ kef){
  __shared__ unsigned long long keys[CAND_CAP];
  __shared__ unsigned long long red[8];
  const int b = blockIdx.x;
  const int tid = threadIdx.x;
  int n = (int)min(cnt[b], (unsigned)CAND_CAP);
  const int nr = (n + 511) & ~511;           // scan bound, multiple of 512
  for (int i = tid; i < nr; i += 512){
    unsigned long long kk = 0ull;
    if (i < n){
      unsigned o = ordkey(cval[b * CAND_CAP + i]);
      kk = ((unsigned long long)o << 32) | (unsigned long long)(0xFFFFFFFFu - cidx[b * CAND_CAP + i]);
    }
    keys[i] = kk;
  }
  __syncthreads();
  int K = top_ks[b];
  K = K < 1 ? 1 : (K > 63 ? 63 : K);
  K = K < n ? K : n;
  for (int k = 0; k < K; ++k){
    unsigned long long best = 0ull;
    for (int i = tid; i < nr; i += 512){
      unsigned long long xx = keys[i];
      best = xx > best ? xx : best;
    }
#pragma unroll
    for (int off = 32; off; off >>= 1){
      unsigned long long o = __shfl_down(best, off);
      best = o > best ? o : best;
    }
    if ((tid & 63) == 0) red[tid >> 6] = best;
    __syncthreads();
    {
      unsigned long long m01 = red[0] > red[1] ? red[0] : red[1];
      unsigned long long m23 = red[2] > red[3] ? red[2] : red[3];
      unsigned long long m45 = red[4] > red[5] ? red[4] : red[5];
      unsigned long long m67 = red[6] > red[7] ? red[6] : red[7];
      unsigned long long a = m01 > m23 ? m01 : m23;
      unsigned long long c2 = m45 > m67 ? m45 : m67;
      best = a > c2 ? a : c2;
    }
    for (int i = tid; i < nr; i += 512)
      if (keys[i] == best) keys[i] = 0ull;
    if (tid == 0){
      tv[b * 64 + k] = ordinv((unsigned)(best >> 32));
      ti[b * 64 + k] = 0xFFFFFFFFu - (unsigned)(best & 0xFFFFFFFFu);
    }
    __syncthreads();
  }
  if (tid == 0) kef[b] = (unsigned)K;
}

// top-p mask on sorted list + gumbel argmax -> token (written as float)
__global__ __launch_bounds__(64) void Sampler_sample(const float* __restrict__ tv,
    const unsigned* __restrict__ ti, const unsigned* __restrict__ kef,
    const float* __restrict__ Mb, const float* __restrict__ Zp,
    const float* __restrict__ top_ps, float* __restrict__ out_tok){
  const int b = blockIdx.x;
  const int k = threadIdx.x;
  const int K = (int)kef[b];
  const float M = Mb[b], tp = top_ps[b];
  float Z = 0.f;
#pragma unroll
  for (int s = 0; s < 16; ++s) Z += Zp[b * 16 + s];
  float p = 0.f, lv = 0.f; unsigned iv = 0xFFFFFFFFu;
  if (k < K){
    lv = tv[b * 64 + k];
    iv = ti[b * 64 + k];
    p = expf(lv - M) / Z;
  }
  float incl = p;
#pragma unroll
  for (int off = 1; off < 64; off <<= 1){
    float t = __shfl_up(incl, off);
    if (k >= off) incl += t;
  }
  float excl = incl - p;
  float val = -3.4e38f; unsigned idx = 0xFFFFFFFFu;
  if (k < K && excl <= tp){
    val = lv + gumbel_at((uint32_t)b, iv);
    idx = iv;
  }
#pragma unroll
  for (int off = 32; off; off >>= 1){
    float ov = __shfl_down(val, off);
    unsigned oi = __shfl_down(idx, off);
    if (ov > val || (ov == val && oi < idx)){ val = ov; idx = oi; }
  }
  if (k == 0) out_tok[b] = (float)idx;
}

extern "C" void kernel_launch(void* const* d_in, const int* in_sizes, int n_in,
                              void* d_out, int out_size, void* d_ws, size_t ws_size,
                              hipStream_t stream){
  (void)in_sizes; (void)n_in; (void)out_size; (void)ws_size;
  const float* x      = (const float*)d_in[0];
  const float* emb    = (const float*)d_in[1];
  const float* ebias  = (const float*)d_in[2];
  const float* top_ps = (const float*)d_in[3];
  const int*   out_pos= (const int*)d_in[4];
  const int*   top_ks = (const int*)d_in[5];

  float* out    = (float*)d_out;       // [0..63] tokens (as float), then logits [64][V]
  float* logits = out + 64;

  // workspace layout
  unsigned short* hhi = (unsigned short*)d_ws;                    // packed A hi [64][2048] bf16
  unsigned short* hlo = hhi + (size_t)B_ * D_;                    // packed A lo
  char* wp = (char*)d_ws + (size_t)B_ * D_ * 4;                   // after 512KB
  float*    pm   = (float*)wp;             wp += (size_t)NBLK * 64 * 4;
  float*    Mb   = (float*)wp;             wp += 64 * 4;
  float*    Zp   = (float*)wp;             wp += 64 * 16 * 4;
  unsigned* cnt  = (unsigned*)wp;          wp += 64 * 4;
  unsigned* kef  = (unsigned*)wp;          wp += 64 * 4;
  float*    tv   = (float*)wp;             wp += 64 * 64 * 4;
  unsigned* ti   = (unsigned*)wp;          wp += 64 * 64 * 4;
  float*    cval = (float*)wp;             wp += (size_t)64 * CAND_CAP * 4;
  unsigned* cidx = (unsigned*)wp;          wp += (size_t)64 * CAND_CAP * 4;

  hipLaunchKernelGGL(Sampler_gather,   dim3((B_ * D_ + 255) / 256), dim3(256), 0, stream, x, out_pos, hhi, hlo, cnt);
  hipLaunchKernelGGL(Sampler_gemm,     dim3(NBLK), dim3(256), 0, stream, hhi, hlo, emb, ebias, logits, pm);
  hipLaunchKernelGGL(Sampler_collectZ, dim3(1024), dim3(256), 0, stream, logits, pm, Mb, Zp, cnt, cval, cidx);
  hipLaunchKernelGGL(Sampler_topk,     dim3(64), dim3(512), 0, stream, cnt, cval, cidx, top_ks, tv, ti, kef);
  hipLaunchKernelGGL(Sampler_sample,   dim3(64), dim3(64), 0, stream, tv, ti, kef, Mb, Zp, top_ps, out);
}